// Round 5
// baseline (2765.174 us; speedup 1.0000x reference)
//
#include <hip/hip_runtime.h>
#include <hip/hip_bf16.h>
#include <math.h>

#define NUM_HEADS 16
#define HEAD_DIM  128
#define SEQ       2048
#define DM        2048
#define BATCH     4
#define M_ROWS    (BATCH * SEQ)   // 8192

typedef short  short8 __attribute__((ext_vector_type(8)));
typedef float  f32x4  __attribute__((ext_vector_type(4)));

__device__ inline unsigned short f2bf(float f) {
    union { float f; unsigned u; } x; x.f = f;
    unsigned r = x.u + 0x7FFF + ((x.u >> 16) & 1);   // RNE
    return (unsigned short)(r >> 16);
}

__device__ inline float bf2f(unsigned short u) {
    union { unsigned u; float f; } x; x.u = ((unsigned)u) << 16;
    return x.f;
}

// ---------------------------------------------------------------------------
// splitk: fp32 -> bf16 hi/lo, done ONCE per element. Memory-bound. (unchanged)
// ---------------------------------------------------------------------------
__global__ __launch_bounds__(256)
void splitk(const float* __restrict__ src, unsigned short* __restrict__ dh,
            unsigned short* __restrict__ dl, int n4) {
    const int stride = gridDim.x * 256;
    for (int i = blockIdx.x * 256 + threadIdx.x; i < n4; i += stride) {
        const float4 v = ((const float4*)src)[i];
        ushort4 h, l;
        h.x = f2bf(v.x); l.x = f2bf(v.x - bf2f(h.x));
        h.y = f2bf(v.y); l.y = f2bf(v.y - bf2f(h.y));
        h.z = f2bf(v.z); l.z = f2bf(v.z - bf2f(h.z));
        h.w = f2bf(v.w); l.w = f2bf(v.w - bf2f(h.w));
        ((ushort4*)dh)[i] = h;
        ((ushort4*)dl)[i] = l;
    }
}

#define BKT  32
#define LDST 40

// ---------------------------------------------------------------------------
// mgemm2: pre-split bf16x2 MFMA GEMM. (unchanged, harness-proven)
// ---------------------------------------------------------------------------
__global__ __launch_bounds__(256)
void mgemm2(const unsigned short* __restrict__ Ah, const unsigned short* __restrict__ Al,
            const unsigned short* __restrict__ Ag,
            const unsigned short* __restrict__ Bh, const unsigned short* __restrict__ Bl,
            unsigned short* __restrict__ Cb, float* __restrict__ Cf, int mode) {
    __shared__ __align__(16) unsigned short AsH[128 * LDST];
    __shared__ __align__(16) unsigned short AsL[128 * LDST];
    __shared__ __align__(16) unsigned short BsH[128 * LDST];
    __shared__ __align__(16) unsigned short BsL[128 * LDST];

    const int tid = threadIdx.x;
    const int lane = tid & 63, wave = tid >> 6;
    const int lo = lane & 15, hi = lane >> 4;
    const int wm = wave >> 1, wn = wave & 1;
    const int tm = blockIdx.y * 128, tn = blockIdx.x * 128;
    const bool split = (Ag == nullptr);

    const int sr = tid >> 2;          // 0..63 staging row (two j-passes: +0,+64)
    const int sc = (tid & 3) * 8;     // 0,8,16,24 ushort offset (16B chunks)

    f32x4 acc[4][4];
    #pragma unroll
    for (int mf = 0; mf < 4; ++mf)
        #pragma unroll
        for (int nf = 0; nf < 4; ++nf) acc[mf][nf] = (f32x4){0.f, 0.f, 0.f, 0.f};

    for (int k0 = 0; k0 < DM; k0 += BKT) {
        if (k0) __syncthreads();
        #pragma unroll
        for (int j = 0; j < 2; ++j) {
            const int r = j * 64 + sr;
            if (split) {
                *(short8*)&AsH[r * LDST + sc] =
                    *(const short8*)&Ah[(size_t)(tm + r) * DM + k0 + sc];
                *(short8*)&AsL[r * LDST + sc] =
                    *(const short8*)&Al[(size_t)(tm + r) * DM + k0 + sc];
            } else {
                const int row = tm + r;
                const int b = row >> 11, s = row & (SEQ - 1);
                const int hh = k0 >> 7, dd = (k0 & (HEAD_DIM - 1)) + sc;
                *(short8*)&AsH[r * LDST + sc] = *(const short8*)
                    &Ag[(((size_t)b * NUM_HEADS + hh) * SEQ + s) * HEAD_DIM + dd];
            }
            *(short8*)&BsH[r * LDST + sc] =
                *(const short8*)&Bh[(size_t)(tn + r) * DM + k0 + sc];
            *(short8*)&BsL[r * LDST + sc] =
                *(const short8*)&Bl[(size_t)(tn + r) * DM + k0 + sc];
        }
        __syncthreads();

        short8 a0[4], b0[4], tf[4];
        #pragma unroll
        for (int mf = 0; mf < 4; ++mf)
            a0[mf] = *(const short8*)&AsH[(wm * 64 + mf * 16 + lo) * LDST + hi * 8];
        #pragma unroll
        for (int nf = 0; nf < 4; ++nf)
            b0[nf] = *(const short8*)&BsH[(wn * 64 + nf * 16 + lo) * LDST + hi * 8];
        #pragma unroll
        for (int mf = 0; mf < 4; ++mf)
            #pragma unroll
            for (int nf = 0; nf < 4; ++nf)
                acc[mf][nf] = __builtin_amdgcn_mfma_f32_16x16x32_bf16(
                    a0[mf], b0[nf], acc[mf][nf], 0, 0, 0);
        if (split) {
            #pragma unroll
            for (int mf = 0; mf < 4; ++mf)
                tf[mf] = *(const short8*)&AsL[(wm * 64 + mf * 16 + lo) * LDST + hi * 8];
            #pragma unroll
            for (int mf = 0; mf < 4; ++mf)
                #pragma unroll
                for (int nf = 0; nf < 4; ++nf)
                    acc[mf][nf] = __builtin_amdgcn_mfma_f32_16x16x32_bf16(
                        tf[mf], b0[nf], acc[mf][nf], 0, 0, 0);
        }
        #pragma unroll
        for (int nf = 0; nf < 4; ++nf)
            tf[nf] = *(const short8*)&BsL[(wn * 64 + nf * 16 + lo) * LDST + hi * 8];
        #pragma unroll
        for (int mf = 0; mf < 4; ++mf)
            #pragma unroll
            for (int nf = 0; nf < 4; ++nf)
                acc[mf][nf] = __builtin_amdgcn_mfma_f32_16x16x32_bf16(
                    a0[mf], tf[nf], acc[mf][nf], 0, 0, 0);
    }

    // ---- epilogue ----
    const int r0 = tm + wm * 64, c0 = tn + wn * 64;
    #pragma unroll
    for (int mf = 0; mf < 4; ++mf) {
        #pragma unroll
        for (int nf = 0; nf < 4; ++nf) {
            const int col = c0 + nf * 16 + lo;
            if (mode == 0) {
                #pragma unroll
                for (int i = 0; i < 4; ++i) {
                    const int row = r0 + mf * 16 + hi * 4 + i;
                    Cf[(size_t)row * DM + col] = acc[mf][nf][i];
                }
            } else if (mode == 3) {
                const int row0 = r0 + mf * 16 + hi * 4;
                const int b = row0 >> 11, s0 = row0 & (SEQ - 1);
                const int hh = col >> 7, dd = col & (HEAD_DIM - 1);
                ushort4 u;
                u.x = f2bf(acc[mf][nf][0]); u.y = f2bf(acc[mf][nf][1]);
                u.z = f2bf(acc[mf][nf][2]); u.w = f2bf(acc[mf][nf][3]);
                *(ushort4*)&Cb[(((size_t)b * NUM_HEADS + hh) * HEAD_DIM + dd) * SEQ + s0] = u;
            } else {
                #pragma unroll
                for (int i = 0; i < 4; ++i) {
                    const int row = r0 + mf * 16 + hi * 4 + i;
                    const int s = row & (SEQ - 1);
                    float val = acc[mf][nf][i];
                    if (mode == 2) {
                        const float partner = __shfl_xor(val, 1, 64);
                        const int fi = (col & (HEAD_DIM - 1)) >> 1;
                        const float ang = (float)s *
                            expf((float)fi * (-9.210340371976184f / 64.f));
                        float sn, cs;
                        sincosf(ang, &sn, &cs);
                        if ((col & 1) == 0) val = val * cs - partner * sn;
                        else                val = val * cs + partner * sn;
                    }
                    const int b = row >> 11;
                    const int hh = col >> 7, dd = col & (HEAD_DIM - 1);
                    Cb[(((size_t)b * NUM_HEADS + hh) * SEQ + s) * HEAD_DIM + dd] = f2bf(val);
                }
            }
        }
    }
}

// ---------------------------------------------------------------------------
// mgemm (on-the-fly-split): FALLBACK when ws too small. (unchanged)
// ---------------------------------------------------------------------------
__global__ __launch_bounds__(256)
void mgemm(const float* __restrict__ Af, const unsigned short* __restrict__ Ag,
           const float* __restrict__ B, unsigned short* __restrict__ Cb,
           float* __restrict__ Cf, int mode) {
    __shared__ __align__(16) unsigned short AsH[128 * LDST];
    __shared__ __align__(16) unsigned short AsL[128 * LDST];
    __shared__ __align__(16) unsigned short BsH[128 * LDST];
    __shared__ __align__(16) unsigned short BsL[128 * LDST];

    const int tid = threadIdx.x;
    const int lane = tid & 63, wave = tid >> 6;
    const int lo = lane & 15, hi = lane >> 4;
    const int wm = wave >> 1, wn = wave & 1;
    const int tm = blockIdx.y * 128, tn = blockIdx.x * 128;
    const bool split = (Ag == nullptr);

    const int sr = tid >> 3;
    const int sc = (tid & 7) * 4;

    f32x4 acc[4][4];
    #pragma unroll
    for (int mf = 0; mf < 4; ++mf)
        #pragma unroll
        for (int nf = 0; nf < 4; ++nf) acc[mf][nf] = (f32x4){0.f, 0.f, 0.f, 0.f};

    for (int k0 = 0; k0 < DM; k0 += BKT) {
        if (k0) __syncthreads();
        #pragma unroll
        for (int it = 0; it < 4; ++it) {
            const int r = it * 32 + sr;
            if (split) {
                const float4 v = *(const float4*)&Af[(size_t)(tm + r) * DM + k0 + sc];
                ushort4 h, l;
                h.x = f2bf(v.x); l.x = f2bf(v.x - bf2f(h.x));
                h.y = f2bf(v.y); l.y = f2bf(v.y - bf2f(h.y));
                h.z = f2bf(v.z); l.z = f2bf(v.z - bf2f(h.z));
                h.w = f2bf(v.w); l.w = f2bf(v.w - bf2f(h.w));
                *(ushort4*)&AsH[r * LDST + sc] = h;
                *(ushort4*)&AsL[r * LDST + sc] = l;
            } else {
                const int row = tm + r;
                const int b = row >> 11, s = row & (SEQ - 1);
                const int k = k0 + sc;
                const int hh = k >> 7, dd = k & (HEAD_DIM - 1);
                const ushort4 u = *(const ushort4*)
                    &Ag[(((size_t)b * NUM_HEADS + hh) * SEQ + s) * HEAD_DIM + dd];
                *(ushort4*)&AsH[r * LDST + sc] = u;
            }
        }
        #pragma unroll
        for (int it = 0; it < 4; ++it) {
            const int r = it * 32 + sr;
            const float4 v = *(const float4*)&B[(size_t)(tn + r) * DM + k0 + sc];
            ushort4 h, l;
            h.x = f2bf(v.x); l.x = f2bf(v.x - bf2f(h.x));
            h.y = f2bf(v.y); l.y = f2bf(v.y - bf2f(h.y));
            h.z = f2bf(v.z); l.z = f2bf(v.z - bf2f(h.z));
            h.w = f2bf(v.w); l.w = f2bf(v.w - bf2f(h.w));
            *(ushort4*)&BsH[r * LDST + sc] = h;
            *(ushort4*)&BsL[r * LDST + sc] = l;
        }
        __syncthreads();

        short8 a0[4], b0[4], tf[4];
        #pragma unroll
        for (int mf = 0; mf < 4; ++mf)
            a0[mf] = *(const short8*)&AsH[(wm * 64 + mf * 16 + lo) * LDST + hi * 8];
        #pragma unroll
        for (int nf = 0; nf < 4; ++nf)
            b0[nf] = *(const short8*)&BsH[(wn * 64 + nf * 16 + lo) * LDST + hi * 8];
        #pragma unroll
        for (int mf = 0; mf < 4; ++mf)
            #pragma unroll
            for (int nf = 0; nf < 4; ++nf)
                acc[mf][nf] = __builtin_amdgcn_mfma_f32_16x16x32_bf16(
                    a0[mf], b0[nf], acc[mf][nf], 0, 0, 0);
        if (split) {
            #pragma unroll
            for (int mf = 0; mf < 4; ++mf)
                tf[mf] = *(const short8*)&AsL[(wm * 64 + mf * 16 + lo) * LDST + hi * 8];
            #pragma unroll
            for (int mf = 0; mf < 4; ++mf)
                #pragma unroll
                for (int nf = 0; nf < 4; ++nf)
                    acc[mf][nf] = __builtin_amdgcn_mfma_f32_16x16x32_bf16(
                        tf[mf], b0[nf], acc[mf][nf], 0, 0, 0);
        }
        #pragma unroll
        for (int nf = 0; nf < 4; ++nf)
            tf[nf] = *(const short8*)&BsL[(wn * 64 + nf * 16 + lo) * LDST + hi * 8];
        #pragma unroll
        for (int mf = 0; mf < 4; ++mf)
            #pragma unroll
            for (int nf = 0; nf < 4; ++nf)
                acc[mf][nf] = __builtin_amdgcn_mfma_f32_16x16x32_bf16(
                    a0[mf], tf[nf], acc[mf][nf], 0, 0, 0);
    }

    const int r0 = tm + wm * 64, c0 = tn + wn * 64;
    #pragma unroll
    for (int mf = 0; mf < 4; ++mf) {
        #pragma unroll
        for (int nf = 0; nf < 4; ++nf) {
            const int col = c0 + nf * 16 + lo;
            if (mode == 0) {
                #pragma unroll
                for (int i = 0; i < 4; ++i) {
                    const int row = r0 + mf * 16 + hi * 4 + i;
                    Cf[(size_t)row * DM + col] = acc[mf][nf][i];
                }
            } else if (mode == 3) {
                const int row0 = r0 + mf * 16 + hi * 4;
                const int b = row0 >> 11, s0 = row0 & (SEQ - 1);
                const int hh = col >> 7, dd = col & (HEAD_DIM - 1);
                ushort4 u;
                u.x = f2bf(acc[mf][nf][0]); u.y = f2bf(acc[mf][nf][1]);
                u.z = f2bf(acc[mf][nf][2]); u.w = f2bf(acc[mf][nf][3]);
                *(ushort4*)&Cb[(((size_t)b * NUM_HEADS + hh) * HEAD_DIM + dd) * SEQ + s0] = u;
            } else {
                #pragma unroll
                for (int i = 0; i < 4; ++i) {
                    const int row = r0 + mf * 16 + hi * 4 + i;
                    const int s = row & (SEQ - 1);
                    float val = acc[mf][nf][i];
                    if (mode == 2) {
                        const float partner = __shfl_xor(val, 1, 64);
                        const int fi = (col & (HEAD_DIM - 1)) >> 1;
                        const float ang = (float)s *
                            expf((float)fi * (-9.210340371976184f / 64.f));
                        float sn, cs;
                        sincosf(ang, &sn, &cs);
                        if ((col & 1) == 0) val = val * cs - partner * sn;
                        else                val = val * cs + partner * sn;
                    }
                    const int b = row >> 11;
                    const int hh = col >> 7, dd = col & (HEAD_DIM - 1);
                    Cb[(((size_t)b * NUM_HEADS + hh) * SEQ + s) * HEAD_DIM + dd] = f2bf(val);
                }
            }
        }
    }
}

// ---------------------------------------------------------------------------
// MFMA flash attention (causal), bf16, f32 accumulate.
// OCCUPANCY FIX: one 64-row q-tile per block, grid = 32 x 64 = 2048 blocks.
// VGPR=64 + LDS 9KB + __launch_bounds__(256,8) -> 8 blocks/CU = 32 waves/CU
// (was grid-capped at 16 waves/CU = 47% measured). Imbalance across blocks is
// absorbed: whole grid co-resident from t=0, each CU hosts a qt mix.
// XCD-chunked swizzle: each XCD's 256 blocks cover 8 consecutive bh -> K/V
// working set ~8MB/XCD-L2 instead of 64 bh thrashing all 8 L2s.
// Diagonal mask hoisted out of the main KV loop (uniform-false before).
// ---------------------------------------------------------------------------
__global__ __launch_bounds__(256, 8)
void mattn(const unsigned short* __restrict__ Q, const unsigned short* __restrict__ K,
           const unsigned short* __restrict__ Vt, unsigned short* __restrict__ Y) {
    __shared__ __align__(16) unsigned short Plds[4][16][72];
    const int tid = threadIdx.x, wave = tid >> 6, lane = tid & 63;
    const int lo = lane & 15, hi = lane >> 4;

    // XCD-chunked swizzle (bijective: 2048 = 8 * 256)
    const int flat = blockIdx.x + (int)gridDim.x * blockIdx.y;   // 0..2047
    const int v = (flat & 7) * 256 + (flat >> 3);
    const int qt = v & 31;            // q-tile 0..31
    const int bh = v >> 5;            // 0..63
    const int q0 = qt * 64 + wave * 16;

    const size_t baseQ = (size_t)bh * SEQ * HEAD_DIM;
    const size_t baseV = (size_t)bh * HEAD_DIM * SEQ;
    const float kscale = 0.08838834764831845f * 1.4426950408889634f;

    short8 qf[4];
    {
        const unsigned short* qrow = Q + baseQ + (size_t)(q0 + lo) * HEAD_DIM + hi * 8;
        #pragma unroll
        for (int c = 0; c < 4; ++c) qf[c] = *(const short8*)(qrow + c * 32);
    }

    f32x4 o[8];
    #pragma unroll
    for (int dt = 0; dt < 8; ++dt) o[dt] = (f32x4){0.f, 0.f, 0.f, 0.f};
    float m[4], l[4];
    #pragma unroll
    for (int i = 0; i < 4; ++i) { m[i] = -1e30f; l[i] = 0.f; }

    auto tile = [&](int kv0, bool diag) {
        // ---- S = Q*K^T ----
        f32x4 s[4];
        #pragma unroll
        for (int t = 0; t < 4; ++t) {
            f32x4 acc = {0.f, 0.f, 0.f, 0.f};
            const unsigned short* krow =
                K + baseQ + (size_t)(kv0 + t * 16 + lo) * HEAD_DIM + hi * 8;
            #pragma unroll
            for (int c = 0; c < 4; ++c) {
                short8 kf = *(const short8*)(krow + c * 32);
                acc = __builtin_amdgcn_mfma_f32_16x16x32_bf16(qf[c], kf, acc, 0, 0, 0);
            }
            s[t] = acc;
        }

        // ---- scale (+ causal mask only on the diagonal tile) ----
        #pragma unroll
        for (int t = 0; t < 4; ++t)
            #pragma unroll
            for (int i = 0; i < 4; ++i) {
                float sv = s[t][i] * kscale;
                if (diag && (kv0 + t * 16 + lo > q0 + hi * 4 + i)) sv = -1e30f;
                s[t][i] = sv;
            }

        // ---- online softmax: row max over 16 cols ----
        float corr[4];
        #pragma unroll
        for (int i = 0; i < 4; ++i) {
            float mv = fmaxf(fmaxf(s[0][i], s[1][i]), fmaxf(s[2][i], s[3][i]));
            mv = fmaxf(mv, __shfl_xor(mv, 1, 64));
            mv = fmaxf(mv, __shfl_xor(mv, 2, 64));
            mv = fmaxf(mv, __shfl_xor(mv, 4, 64));
            mv = fmaxf(mv, __shfl_xor(mv, 8, 64));
            const float mn = fmaxf(m[i], mv);
            corr[i] = exp2f(m[i] - mn);
            m[i] = mn;
        }

        // ---- P = exp2(s - m): row-sum + bf16 spill to LDS ----
        float rs[4] = {0.f, 0.f, 0.f, 0.f};
        #pragma unroll
        for (int t = 0; t < 4; ++t)
            #pragma unroll
            for (int i = 0; i < 4; ++i) {
                const float p = exp2f(s[t][i] - m[i]);
                rs[i] += p;
                Plds[wave][hi * 4 + i][t * 16 + lo] = f2bf(p);
            }
        #pragma unroll
        for (int i = 0; i < 4; ++i) {
            float sv = rs[i];
            sv += __shfl_xor(sv, 1, 64);
            sv += __shfl_xor(sv, 2, 64);
            sv += __shfl_xor(sv, 4, 64);
            sv += __shfl_xor(sv, 8, 64);
            l[i] = l[i] * corr[i] + sv;
        }

        // ---- rescale O ----
        #pragma unroll
        for (int dt = 0; dt < 8; ++dt)
            #pragma unroll
            for (int i = 0; i < 4; ++i) o[dt][i] *= corr[i];

        // ---- P A-frags from LDS (wave-private) ----
        short8 pa[2];
        #pragma unroll
        for (int ks = 0; ks < 2; ++ks)
            pa[ks] = *(const short8*)&Plds[wave][lo][ks * 32 + hi * 8];

        // ---- O += P * V: loads batched 8-ahead ----
        #pragma unroll
        for (int dh = 0; dh < 2; ++dh) {
            short8 vf[8];
            #pragma unroll
            for (int q = 0; q < 8; ++q) {
                const int dt = dh * 4 + (q >> 1), ks = q & 1;
                vf[q] = *(const short8*)(Vt + baseV +
                    (size_t)(dt * 16 + lo) * SEQ + kv0 + ks * 32 + hi * 8);
            }
            #pragma unroll
            for (int q = 0; q < 8; ++q) {
                const int dt = dh * 4 + (q >> 1), ks = q & 1;
                o[dt] = __builtin_amdgcn_mfma_f32_16x16x32_bf16(
                    pa[ks], vf[q], o[dt], 0, 0, 0);
            }
        }
    };

    #pragma unroll 1
    for (int kt = 0; kt < qt; ++kt) tile(kt * 64, false);   // off-diagonal
    tile(qt * 64, true);                                    // diagonal tile

    // ---- epilogue: normalize and store ----
    #pragma unroll
    for (int dt = 0; dt < 8; ++dt)
        #pragma unroll
        for (int i = 0; i < 4; ++i) {
            const float y = o[dt][i] / l[i];
            Y[baseQ + (size_t)(q0 + hi * 4 + i) * HEAD_DIM + dt * 16 + lo] = f2bf(y);
        }
}

extern "C" void kernel_launch(void* const* d_in, const int* in_sizes, int n_in,
                              void* d_out, int out_size, void* d_ws, size_t ws_size,
                              hipStream_t stream) {
    // ---- Runtime input identification (robust to ordering surprises) ----
    int xi = -1, pi = -1, wi[4] = {-1, -1, -1, -1};
    int nw = 0;
    for (int i = 0; i < n_in && i < 8; ++i) {
        const long long sz = in_sizes[i];
        if (sz == 16777216) xi = i;
        else if (sz == 2048) pi = i;
        else if (sz == 4194304 && nw < 4) wi[nw++] = i;
    }
    int iq, ik, iv, io;
    if (xi < 0 || nw < 4) {
        xi = 0; iq = 2; ik = 3; iv = 4; io = 5;   // documented dict order
    } else if (pi == 4 && xi == 5) {
        ik = wi[0]; io = wi[1]; iq = wi[2]; iv = wi[3];   // alphabetical
    } else {
        iq = wi[0]; ik = wi[1]; iv = wi[2]; io = wi[3];   // dict order
    }

    const float* x  = (const float*)d_in[xi];
    const float* Wq = (const float*)d_in[iq];
    const float* Wk = (const float*)d_in[ik];
    const float* Wv = (const float*)d_in[iv];
    const float* Wo = (const float*)d_in[io];
    float* out = (float*)d_out;

    unsigned short* ws16 = (unsigned short*)d_ws;
    unsigned short* Qb = ws16;                       // 1<<24 ushorts (32 MiB)
    unsigned short* Kb = Qb + (1ull << 24);
    unsigned short* Vt = Kb + (1ull << 24);

    dim3 blk(256);
    dim3 gg(DM / 128, M_ROWS / 128);   // (16, 64)
    dim3 ga(SEQ / 64, BATCH * NUM_HEADS);   // (32, 64) = 2048 blocks

    // Pre-split path needs: Qb,Kb,Vt,xh,xl (5 x 1<<24) + Wh,Wl (2 x 1<<22)
    const size_t NEED = ((5ull << 24) + (2ull << 22)) * 2ull;
    if (ws_size >= NEED) {
        unsigned short* xh = Vt + (1ull << 24);
        unsigned short* xl = xh + (1ull << 24);
        unsigned short* Wh = xl + (1ull << 24);
        unsigned short* Wl = Wh + (1ull << 22);
        const int nx4 = (M_ROWS * DM) / 4;           // 4,194,304
        const int nw4 = (DM * DM) / 4;               // 1,048,576
        dim3 gs(1024);

        splitk<<<gs, blk, 0, stream>>>(x,  xh, xl, nx4);
        splitk<<<gs, blk, 0, stream>>>(Wq, Wh, Wl, nw4);
        mgemm2<<<gg, blk, 0, stream>>>(xh, xl, nullptr, Wh, Wl, Qb, nullptr, 2);
        splitk<<<gs, blk, 0, stream>>>(Wk, Wh, Wl, nw4);
        mgemm2<<<gg, blk, 0, stream>>>(xh, xl, nullptr, Wh, Wl, Kb, nullptr, 2);
        splitk<<<gs, blk, 0, stream>>>(Wv, Wh, Wl, nw4);
        mgemm2<<<gg, blk, 0, stream>>>(xh, xl, nullptr, Wh, Wl, Vt, nullptr, 3);
        mattn<<<ga, blk, 0, stream>>>(Qb, Kb, Vt, Qb);
        splitk<<<gs, blk, 0, stream>>>(Wo, Wh, Wl, nw4);
        mgemm2<<<gg, blk, 0, stream>>>(nullptr, nullptr, Qb, Wh, Wl, nullptr, out, 0);
    } else {
        // Fallback: on-the-fly split path.
        mgemm<<<gg, blk, 0, stream>>>(x, nullptr, Wq, Qb, nullptr, 2);
        mgemm<<<gg, blk, 0, stream>>>(x, nullptr, Wk, Kb, nullptr, 2);
        mgemm<<<gg, blk, 0, stream>>>(x, nullptr, Wv, Vt, nullptr, 3);
        mattn<<<ga, blk, 0, stream>>>(Qb, Kb, Vt, Qb);
        mgemm<<<gg, blk, 0, stream>>>(nullptr, Qb, Wo, nullptr, out, 0);
    }
}